// Round 7
// baseline (392.368 us; speedup 1.0000x reference)
//
#include <hip/hip_runtime.h>
#include <hip/hip_bf16.h>

typedef __hip_bfloat16 bf16;
typedef short s16x8 __attribute__((ext_vector_type(8)));
typedef float f32x4 __attribute__((ext_vector_type(4)));

#define N_NODES 50000
#define NPAD    50048          // multiple of 64
#define E_EDGES 600000
#define HID     128
#define HEADS   4
#define SCAN_B  196            // ceil(NPAD/256)

// ---- float -> bf16 bits (RNE), finite inputs only ----
__device__ __forceinline__ unsigned short f2bf_bits(float f) {
  unsigned u = __float_as_uint(f);
  u += 0x7fffu + ((u >> 16) & 1u);
  return (unsigned short)(u >> 16);
}
__device__ __forceinline__ float bf2f(unsigned short b) {
  return __uint_as_float(((unsigned)b) << 16);
}
// packed-dword bf16 pair -> floats (1 op each)
__device__ __forceinline__ float lo_f(unsigned v) { return __uint_as_float(v << 16); }
__device__ __forceinline__ float hi_f(unsigned v) { return __uint_as_float(v & 0xffff0000u); }

__device__ __forceinline__ float lrelu(float v) { return v >= 0.f ? v : 0.2f * v; }

// ---- runtime dtype detection ----
// flags[0]=1 -> float tensors are fp32 (else bf16). flags[1]=1 -> indices are int64.
__global__ __launch_bounds__(256) void detect_kernel(const unsigned short* __restrict__ xb,
                                                     const int* __restrict__ ei,
                                                     int* __restrict__ flags) {
  int t = threadIdx.x;
  __shared__ int cnt[2];
  if (t < 2) cnt[t] = 0;
  __syncthreads();
  unsigned short v = xb[2 * t];
  int ex = (v >> 7) & 0xFF;
  if (ex < 119 || ex > 135) atomicAdd(&cnt[0], 1);
  if (ei[2 * t + 1] != 0) atomicAdd(&cnt[1], 1);
  __syncthreads();
  if (t == 0) {
    flags[0] = (cnt[0] > 64) ? 1 : 0;
    flags[1] = (cnt[1] == 0) ? 1 : 0;
  }
}

__global__ __launch_bounds__(256) void zero_int_kernel(int* __restrict__ p, int n) {
  int i = blockIdx.x * 256 + threadIdx.x;
  if (i < n) p[i] = 0;
}

// ---- index conversion + degree histogram: dstA[e], pk[e] = src | (r<<16) ----
__global__ __launch_bounds__(256) void cvt_idx_hist_kernel(const int* __restrict__ eidx,
                                                           const int* __restrict__ etype,
                                                           int* __restrict__ dstA, int* __restrict__ pk,
                                                           int* __restrict__ deg,
                                                           const int* __restrict__ flags) {
  int e = blockIdx.x * 256 + threadIdx.x;
  if (e >= E_EDGES) return;
  int s, d, r;
  if (flags[1]) {
    const long long* e64 = (const long long*)eidx;
    const long long* t64 = (const long long*)etype;
    s = (int)e64[e]; d = (int)e64[E_EDGES + e]; r = (int)t64[e];
  } else {
    s = eidx[e]; d = eidx[E_EDGES + e]; r = etype[e];
  }
  dstA[e] = d;
  pk[e] = s | (r << 16);
  atomicAdd(&deg[d], 1);
}

// ---- float-tensor -> bf16 bits ----
__global__ __launch_bounds__(256) void cvt_xb_kernel(const void* __restrict__ src,
                                                     unsigned short* __restrict__ dst, int n,
                                                     const int* __restrict__ flags) {
  int i = blockIdx.x * 256 + threadIdx.x;
  if (i >= n) return;
  if (flags[0]) dst[i] = f2bf_bits(((const float*)src)[i]);
  else          dst[i] = ((const unsigned short*)src)[i];
}

// ---- W (both layers) [128(in)][128(out)] -> bf16 N-major [l][r][o][i] ----
__global__ __launch_bounds__(256) void cvt_wt_kernel(const void* __restrict__ src0,
                                                     const void* __restrict__ src1,
                                                     unsigned short* __restrict__ dst,
                                                     const int* __restrict__ flags) {
  int idx = blockIdx.x * 256 + threadIdx.x;
  if (idx >= 2 * 2 * HID * HID) return;
  int l = idx >> 15, rem = idx & 32767;
  int r = rem >> 14, i = (rem >> 7) & 127, o = rem & 127;
  const void* src = l ? src1 : src0;
  unsigned short b;
  if (flags[0]) b = f2bf_bits(((const float*)src)[rem]);
  else          b = ((const unsigned short*)src)[rem];
  dst[(size_t)l * 2 * HID * HID + ((size_t)r * HID + o) * HID + i] = b;
}

// ---- small params (Q,K,cb,pb for both layers) -> fp32 block ----
struct P8 { const void* src[8]; int dstoff[8]; int n[8]; };
__global__ __launch_bounds__(256) void cvt_params_kernel(P8 tab, float* __restrict__ base,
                                                         const int* __restrict__ flags) {
  const int f = flags[0];
  for (int k = 0; k < 8; ++k) {
    int n = tab.n[k];
    for (int i = blockIdx.x * 256 + threadIdx.x; i < n; i += gridDim.x * 256) {
      float v = f ? ((const float*)tab.src[k])[i] : bf2f(((const unsigned short*)tab.src[k])[i]);
      base[tab.dstoff[k] + i] = v;
    }
  }
}

// ---- scan stage 1: per-256-block inclusive scan ----
__global__ __launch_bounds__(256) void scan1_kernel(const int* __restrict__ deg,
                                                    int* __restrict__ excl,
                                                    int* __restrict__ bsum) {
  __shared__ int sm[256];
  int t = threadIdx.x, i = blockIdx.x * 256 + t;
  int v = (i < NPAD) ? deg[i] : 0;
  sm[t] = v;
  __syncthreads();
#pragma unroll
  for (int off = 1; off < 256; off <<= 1) {
    int add = (t >= off) ? sm[t - off] : 0;
    __syncthreads();
    sm[t] += add;
    __syncthreads();
  }
  if (i < NPAD) excl[i] = sm[t] - v;
  if (t == 255) bsum[blockIdx.x] = sm[255];
}

// ---- scan stages 2+3 fused: each block redundantly scans bsum, adds prefix ----
__global__ __launch_bounds__(256) void scan23_kernel(const int* __restrict__ excl,
                                                     const int* __restrict__ bsum,
                                                     int* __restrict__ rowstart) {
  __shared__ int sm[256];
  int t = threadIdx.x;
  int v = (t < SCAN_B) ? bsum[t] : 0;
  sm[t] = v;
  __syncthreads();
#pragma unroll
  for (int off = 1; off < 256; off <<= 1) {
    int add = (t >= off) ? sm[t - off] : 0;
    __syncthreads();
    sm[t] += add;
    __syncthreads();
  }
  int bpre = (blockIdx.x > 0) ? sm[blockIdx.x - 1] : 0;   // exclusive block prefix
  int i = blockIdx.x * 256 + t;
  if (i < NPAD) rowstart[i] = excl[i] + bpre;
  if (i == 0) rowstart[NPAD] = E_EDGES;
}

__global__ __launch_bounds__(256) void scatter_kernel(const int* __restrict__ dstA,
                                                      const int* __restrict__ pk,
                                                      const int* __restrict__ rowstart,
                                                      int* __restrict__ cnt,
                                                      int* __restrict__ eord) {
  int e = blockIdx.x * 256 + threadIdx.x;
  if (e >= E_EDGES) return;
  int d = dstA[e];
  int pos = rowstart[d] + atomicAdd(&cnt[d], 1);
  eord[pos] = pk[e];
}

// ====== MFMA GEMM core: one wave -> 64x64, K=128, FULL-K PREFETCH ======
// All 32 fragment loads issue before any MFMA -> one L2 round-trip per wave
// instead of 4 (R6 was latency-bound at 72 VGPR / 4 serialized kc chunks).
__device__ __forceinline__ void wave_gemm64(const unsigned short* __restrict__ Ab, int row0,
                                            const unsigned short* __restrict__ Bt, int colb,
                                            int lane, f32x4 acc[4][4]) {
  const int lm = lane & 15, q = lane >> 4;
  s16x8 af[4][4], bfr[4][4];
#pragma unroll
  for (int kc = 0; kc < 4; ++kc) {
    const int ko = kc * 32 + q * 8;
#pragma unroll
    for (int rt = 0; rt < 4; ++rt)
      af[kc][rt] = *(const s16x8*)(Ab + (size_t)(row0 + rt * 16 + lm) * HID + ko);
  }
#pragma unroll
  for (int kc = 0; kc < 4; ++kc) {
    const int ko = kc * 32 + q * 8;
#pragma unroll
    for (int ct = 0; ct < 4; ++ct)
      bfr[kc][ct] = *(const s16x8*)(Bt + (size_t)(colb + ct * 16 + lm) * HID + ko);
  }
#pragma unroll
  for (int kc = 0; kc < 4; ++kc)
#pragma unroll
    for (int rt = 0; rt < 4; ++rt)
#pragma unroll
      for (int ct = 0; ct < 4; ++ct)
        acc[rt][ct] = __builtin_amdgcn_mfma_f32_16x16x32_bf16(af[kc][rt], bfr[kc][ct], acc[rt][ct], 0, 0, 0);
}

// ---- xw[r,n,:] = h[n,:] @ W[r]; block = 4 waves = 4 (r,colpanel) of SAME rows ----
__global__ __launch_bounds__(256) void gemm_xw_mfma(const unsigned short* __restrict__ hb,
                                                    const unsigned short* __restrict__ Wbt,
                                                    unsigned short* __restrict__ xw) {
  const int wave = threadIdx.x >> 6, lane = threadIdx.x & 63;
  const int row0 = blockIdx.x * 64;
  const int r = wave >> 1, colb = (wave & 1) * 64;
  f32x4 acc[4][4];
#pragma unroll
  for (int a = 0; a < 4; ++a)
#pragma unroll
    for (int b = 0; b < 4; ++b) { f32x4 z = {0.f, 0.f, 0.f, 0.f}; acc[a][b] = z; }
  wave_gemm64(hb, row0, Wbt + (size_t)r * HID * HID, colb, lane, acc);
  const int lm = lane & 15, q = lane >> 4;
#pragma unroll
  for (int rt = 0; rt < 4; ++rt)
#pragma unroll
    for (int i = 0; i < 4; ++i) {
      int row = row0 + rt * 16 + q * 4 + i;
      if (row < N_NODES) {
#pragma unroll
        for (int ct = 0; ct < 4; ++ct) {
          int o = colb + ct * 16 + lm;
          xw[((size_t)r * NPAD + row) * HID + o] = f2bf_bits(acc[rt][ct][i]);
        }
      }
    }
}

// ---- out[n,o] = elu( agg[n,:] @ pW.T + bo ); block = 2 waves = 2 col panels ----
__global__ __launch_bounds__(128) void proj_mfma(const unsigned short* __restrict__ aggb,
                                                 const unsigned short* __restrict__ pWTb,
                                                 const float* __restrict__ bo,
                                                 unsigned short* __restrict__ hbout,
                                                 void* __restrict__ dout,
                                                 const int* __restrict__ flags) {
  const int wave = threadIdx.x >> 6, lane = threadIdx.x & 63;
  const int row0 = blockIdx.x * 64;
  const int colb = wave * 64;
  f32x4 acc[4][4];
#pragma unroll
  for (int a = 0; a < 4; ++a)
#pragma unroll
    for (int b = 0; b < 4; ++b) { f32x4 z = {0.f, 0.f, 0.f, 0.f}; acc[a][b] = z; }
  wave_gemm64(aggb, row0, pWTb, colb, lane, acc);
  const int lm = lane & 15, q = lane >> 4;
  const int f32out = flags[0];
#pragma unroll
  for (int rt = 0; rt < 4; ++rt)
#pragma unroll
    for (int i = 0; i < 4; ++i) {
      int row = row0 + rt * 16 + q * 4 + i;
      if (row < N_NODES) {
#pragma unroll
        for (int ct = 0; ct < 4; ++ct) {
          int o = colb + ct * 16 + lm;
          float v = acc[rt][ct][i] + bo[o];
          v = v > 0.f ? v : expm1f(v);       // ELU
          size_t idx = (size_t)row * HID + o;
          if (dout) {
            if (f32out) ((float*)dout)[idx] = v;
            else        ((unsigned short*)dout)[idx] = f2bf_bits(v);
          } else {
            hbout[idx] = f2bf_bits(v);
          }
        }
      }
    }
}

// ---- WQ/WK fold -> split-bf16 table qkt[l][out16][128], out = qk*8 + r*4 + h ----
__global__ __launch_bounds__(256) void prep_wq_kernel(const unsigned short* __restrict__ Wbt,
                                                      const float* __restrict__ Qf,
                                                      const float* __restrict__ Kf,
                                                      unsigned short* __restrict__ qkt_hi,
                                                      unsigned short* __restrict__ qkt_lo) {
  int idx = blockIdx.x * 256 + threadIdx.x;   // (l,r,i)
  if (idx >= 2 * 2 * HID) return;
  int i = idx & 127, lr = idx >> 7, l = lr >> 1, r = (lr & 1);
  float aq[4] = {0.f, 0.f, 0.f, 0.f}, ak[4] = {0.f, 0.f, 0.f, 0.f};
  const unsigned short* Wb = Wbt + (size_t)lr * HID * HID;   // [o=j][i]
  const float* Qp = Qf + l * HID * HEADS;
  const float* Kp = Kf + l * HID * HEADS;
  for (int j = 0; j < HID; ++j) {
    float w = bf2f(Wb[j * HID + i]);
    float4 q4 = *(const float4*)(Qp + j * 4);
    float4 k4 = *(const float4*)(Kp + j * 4);
    aq[0] += w * q4.x; aq[1] += w * q4.y; aq[2] += w * q4.z; aq[3] += w * q4.w;
    ak[0] += w * k4.x; ak[1] += w * k4.y; ak[2] += w * k4.z; ak[3] += w * k4.w;
  }
  size_t base = (size_t)l * 16 * HID;
#pragma unroll
  for (int h = 0; h < 4; ++h) {
    unsigned short qh = f2bf_bits(aq[h]);
    unsigned short kh = f2bf_bits(ak[h]);
    float qres = aq[h] - bf2f(qh);
    float kres = ak[h] - bf2f(kh);
    qkt_hi[base + (size_t)(r * 4 + h) * HID + i] = qh;
    qkt_lo[base + (size_t)(r * 4 + h) * HID + i] = f2bf_bits(qres);
    qkt_hi[base + (size_t)(8 + r * 4 + h) * HID + i] = kh;
    qkt_lo[base + (size_t)(8 + r * 4 + h) * HID + i] = f2bf_bits(kres);
  }
}

// ---- qk via MFMA: [64 nodes]x[16 outs] per wave, split-bf16 B, full prefetch ----
__global__ __launch_bounds__(256) void qk_mfma_kernel(const unsigned short* __restrict__ hb,
                                                      const unsigned short* __restrict__ qkt_hi,
                                                      const unsigned short* __restrict__ qkt_lo,
                                                      float4* __restrict__ qi4,
                                                      float4* __restrict__ kj4) {
  __shared__ float st[4][16][68];               // [wave][out][node], pad 68 -> conflict-free reads
  const int wave = threadIdx.x >> 6, lane = threadIdx.x & 63;
  const int row0 = blockIdx.x * 256 + wave * 64;
  const int lm = lane & 15, q = lane >> 4;
  if (row0 < NPAD) {
    s16x8 bhi[4], blo[4], af[4][4];
#pragma unroll
    for (int kc = 0; kc < 4; ++kc) {
      const int ko = kc * 32 + q * 8;
      bhi[kc] = *(const s16x8*)(qkt_hi + (size_t)lm * HID + ko);
      blo[kc] = *(const s16x8*)(qkt_lo + (size_t)lm * HID + ko);
    }
#pragma unroll
    for (int kc = 0; kc < 4; ++kc) {
      const int ko = kc * 32 + q * 8;
#pragma unroll
      for (int rt = 0; rt < 4; ++rt)
        af[kc][rt] = *(const s16x8*)(hb + (size_t)(row0 + rt * 16 + lm) * HID + ko);
    }
    f32x4 acc[4];
#pragma unroll
    for (int a = 0; a < 4; ++a) { f32x4 z = {0.f, 0.f, 0.f, 0.f}; acc[a] = z; }
#pragma unroll
    for (int kc = 0; kc < 4; ++kc)
#pragma unroll
      for (int rt = 0; rt < 4; ++rt) {
        acc[rt] = __builtin_amdgcn_mfma_f32_16x16x32_bf16(af[kc][rt], bhi[kc], acc[rt], 0, 0, 0);
        acc[rt] = __builtin_amdgcn_mfma_f32_16x16x32_bf16(af[kc][rt], blo[kc], acc[rt], 0, 0, 0);
      }
    // C layout: col(out)=lm, row(node)=rt*16 + q*4 + i -> stage [out][node] in LDS
#pragma unroll
    for (int rt = 0; rt < 4; ++rt)
      *(f32x4*)&st[wave][lm][rt * 16 + q * 4] = acc[rt];
  }
  __syncthreads();
  if (row0 < NPAD) {
    int n = row0 + lane;
    if (n < N_NODES) {
      float4 v;
      v.x = st[wave][0][lane]; v.y = st[wave][1][lane]; v.z = st[wave][2][lane]; v.w = st[wave][3][lane];
      qi4[n] = v;
      v.x = st[wave][4][lane]; v.y = st[wave][5][lane]; v.z = st[wave][6][lane]; v.w = st[wave][7][lane];
      qi4[NPAD + n] = v;
      v.x = st[wave][8][lane]; v.y = st[wave][9][lane]; v.z = st[wave][10][lane]; v.w = st[wave][11][lane];
      kj4[n] = v;
      v.x = st[wave][12][lane]; v.y = st[wave][13][lane]; v.z = st[wave][14][lane]; v.w = st[wave][15][lane];
      kj4[NPAD + n] = v;
    }
  }
}

// ---- fused per-dst-node: alpha -> segment softmax -> weighted aggregate ----
__global__ __launch_bounds__(256) void edge_fused_kernel(
    const int* __restrict__ rowstart, const int* __restrict__ eord,
    const float4* __restrict__ qi4, const float4* __restrict__ kj4,
    const unsigned short* __restrict__ xw, unsigned short* __restrict__ aggb) {
  __shared__ float wls[4][64][4];
  const int wave = threadIdx.x >> 6, lane = threadIdx.x & 63;
  const int n = blockIdx.x * 4 + wave;          // N_NODES % 4 == 0 -> always valid
  unsigned* outp = (unsigned*)(aggb + ((size_t)n << 7)) + lane;
  const int start = rowstart[n];
  const int deg = rowstart[n + 1] - start;
  if (deg == 0) { *outp = 0u; return; }
  const int hh = lane >> 4;
  const int ch2 = lane << 1;                    // ushort offset within a row
  float2 acc = {0.f, 0.f};
  float ssel;
  if (deg <= 64) {
    int p = 0;
    float a0 = -1e30f, a1 = -1e30f, a2 = -1e30f, a3 = -1e30f;
    if (lane < deg) {
      p = eord[start + lane];
      int s = p & 0xffff, r = p >> 16;
      float4 k4 = kj4[r ? (NPAD + s) : s];
      float4 q4 = r ? qi4[NPAD + n] : qi4[n];
      a0 = lrelu(q4.x + k4.x); a1 = lrelu(q4.y + k4.y);
      a2 = lrelu(q4.z + k4.z); a3 = lrelu(q4.w + k4.w);
    }
    float m0 = a0, m1 = a1, m2 = a2, m3 = a3;
#pragma unroll
    for (int off = 32; off > 0; off >>= 1) {
      m0 = fmaxf(m0, __shfl_xor(m0, off)); m1 = fmaxf(m1, __shfl_xor(m1, off));
      m2 = fmaxf(m2, __shfl_xor(m2, off)); m3 = fmaxf(m3, __shfl_xor(m3, off));
    }
    float w0 = 0.f, w1 = 0.f, w2 = 0.f, w3 = 0.f;
    if (lane < deg) {
      w0 = __expf(a0 - m0); w1 = __expf(a1 - m1);
      w2 = __expf(a2 - m2); w3 = __expf(a3 - m3);
    }
    float s0 = w0, s1 = w1, s2 = w2, s3 = w3;
#pragma unroll
    for (int off = 32; off > 0; off >>= 1) {
      s0 += __shfl_xor(s0, off); s1 += __shfl_xor(s1, off);
      s2 += __shfl_xor(s2, off); s3 += __shfl_xor(s3, off);
    }
    ssel = hh == 0 ? s0 : hh == 1 ? s1 : hh == 2 ? s2 : s3;
    // per-edge weights to LDS (volatile pins write->read ordering, wave-local)
    volatile float* wp = &wls[wave][lane][0];
    wp[0] = w0; wp[1] = w1; wp[2] = w2; wp[3] = w3;
    volatile float* wr = &wls[wave][0][0];
    const int degp = (deg + 3) & ~3;            // pad lanes hold w=0, p=0 (row 0)
    for (int e = 0; e < degp; e += 4) {
      int p0 = __builtin_amdgcn_readlane(p, e);
      int p1 = __builtin_amdgcn_readlane(p, e + 1);
      int p2 = __builtin_amdgcn_readlane(p, e + 2);
      int p3 = __builtin_amdgcn_readlane(p, e + 3);
      // scalar row bases -> SGPR-base loads with per-lane ch2 offset
      unsigned v0 = *(const unsigned*)(xw + ((size_t)((p0 & 0xffff) + (p0 >> 16) * NPAD) << 7) + ch2);
      unsigned v1 = *(const unsigned*)(xw + ((size_t)((p1 & 0xffff) + (p1 >> 16) * NPAD) << 7) + ch2);
      unsigned v2 = *(const unsigned*)(xw + ((size_t)((p2 & 0xffff) + (p2 >> 16) * NPAD) << 7) + ch2);
      unsigned v3 = *(const unsigned*)(xw + ((size_t)((p3 & 0xffff) + (p3 >> 16) * NPAD) << 7) + ch2);
      float we0 = wr[(e + 0) * 4 + hh];
      float we1 = wr[(e + 1) * 4 + hh];
      float we2 = wr[(e + 2) * 4 + hh];
      float we3 = wr[(e + 3) * 4 + hh];
      acc.x = fmaf(lo_f(v0), we0, acc.x); acc.y = fmaf(hi_f(v0), we0, acc.y);
      acc.x = fmaf(lo_f(v1), we1, acc.x); acc.y = fmaf(hi_f(v1), we1, acc.y);
      acc.x = fmaf(lo_f(v2), we2, acc.x); acc.y = fmaf(hi_f(v2), we2, acc.y);
      acc.x = fmaf(lo_f(v3), we3, acc.x); acc.y = fmaf(hi_f(v3), we3, acc.y);
    }
  } else {
    // ---- generic fallback (deg > 64): wave-uniform serial, rare ----
    const float4 q0 = qi4[n], q1 = qi4[NPAD + n];
    float4 m = make_float4(-1e30f, -1e30f, -1e30f, -1e30f);
    for (int e = start; e < start + deg; ++e) {
      int pe = eord[e];
      int s = pe & 0xffff, r = pe >> 16;
      float4 k4 = kj4[(size_t)r * NPAD + s];
      float4 q4 = r ? q1 : q0;
      m.x = fmaxf(m.x, lrelu(q4.x + k4.x)); m.y = fmaxf(m.y, lrelu(q4.y + k4.y));
      m.z = fmaxf(m.z, lrelu(q4.z + k4.z)); m.w = fmaxf(m.w, lrelu(q4.w + k4.w));
    }
    float4 sv = make_float4(0.f, 0.f, 0.f, 0.f);
    for (int e = start; e < start + deg; ++e) {
      int pe = eord[e];
      int s = pe & 0xffff, r = pe >> 16;
      float4 k4 = kj4[(size_t)r * NPAD + s];
      float4 q4 = r ? q1 : q0;
      float w0 = __expf(lrelu(q4.x + k4.x) - m.x);
      float w1 = __expf(lrelu(q4.y + k4.y) - m.y);
      float w2 = __expf(lrelu(q4.z + k4.z) - m.z);
      float w3 = __expf(lrelu(q4.w + k4.w) - m.w);
      sv.x += w0; sv.y += w1; sv.z += w2; sv.w += w3;
      float we = hh == 0 ? w0 : hh == 1 ? w1 : hh == 2 ? w2 : w3;
      unsigned v = *(const unsigned*)(xw + (((size_t)r * NPAD + s) << 7) + ch2);
      acc.x = fmaf(lo_f(v), we, acc.x);
      acc.y = fmaf(hi_f(v), we, acc.y);
    }
    ssel = hh == 0 ? sv.x : hh == 1 ? sv.y : hh == 2 ? sv.z : sv.w;
  }
  float inv = 1.f / (ssel + 1e-16f);
  *outp = (unsigned)f2bf_bits(acc.x * inv) | ((unsigned)f2bf_bits(acc.y * inv) << 16);
}

// ---- both layers: pWTb2[l][o][i] = bf16(pW[o][i]); bo2[l][o] = pb[o] + cb·pW[o,:] ----
__global__ __launch_bounds__(64) void prep_proj_kernel(const void* __restrict__ pW0,
                                                       const void* __restrict__ pW1,
                                                       const float* __restrict__ cbf,
                                                       const float* __restrict__ pbf,
                                                       unsigned short* __restrict__ pWTb2,
                                                       float* __restrict__ bo2,
                                                       const int* __restrict__ flags) {
  int o = blockIdx.x & 127, l = blockIdx.x >> 7, t = threadIdx.x;
  const void* pWraw = l ? pW1 : pW0;
  const float* cb = cbf + l * HID;
  const int f = flags[0];
  float part = 0.f;
#pragma unroll
  for (int i = t; i < HID; i += 64) {
    float w = f ? ((const float*)pWraw)[o * HID + i] : bf2f(((const unsigned short*)pWraw)[o * HID + i]);
    pWTb2[(size_t)l * HID * HID + o * HID + i] = f2bf_bits(w);
    part += cb[i] * w;
  }
#pragma unroll
  for (int off = 32; off > 0; off >>= 1) part += __shfl_xor(part, off);
  if (t == 0) bo2[l * HID + o] = pbf[l * HID + o] + part;
}

extern "C" void kernel_launch(void* const* d_in, const int* in_sizes, int n_in,
                              void* d_out, int out_size, void* d_ws, size_t ws_size,
                              hipStream_t stream) {
  const void* x     = d_in[0];
  const int*  eidx  = (const int*)d_in[1];
  const int*  etype = (const int*)d_in[2];
  const int iW[2] = {3, 9}, iQ[2] = {4, 10}, iK[2] = {5, 11}, icb[2] = {6, 12}, ipW[2] = {7, 13}, ipb[2] = {8, 14};

  float* ws = (float*)d_ws;
  size_t off = 0;
  int*   flags = (int*)(ws + off); off += 16;
  unsigned short* hb   = (unsigned short*)(ws + off); off += (size_t)NPAD * HID / 2;
  unsigned short* xw   = (unsigned short*)(ws + off); off += (size_t)NPAD * HID;       // [2][NPAD][128] bf16
  float* qi   = ws + off; off += (size_t)2 * NPAD * HEADS;
  float* kj   = ws + off; off += (size_t)2 * NPAD * HEADS;
  unsigned short* aggb = (unsigned short*)(ws + off); off += (size_t)NPAD * HID / 2;
  int* dstA = (int*)(ws + off); off += E_EDGES;
  int* pk   = (int*)(ws + off); off += E_EDGES;
  int* eord = (int*)(ws + off); off += E_EDGES;
  int* deg  = (int*)(ws + off); off += NPAD;        // deg|cnt contiguous for one zero pass
  int* cnt  = (int*)(ws + off); off += NPAD;
  int* excl = (int*)(ws + off); off += NPAD;
  int* rowstart = (int*)(ws + off); off += NPAD + 16;
  int* bsum  = (int*)(ws + off); off += 256;
  unsigned short* Wbt   = (unsigned short*)(ws + off); off += (size_t)2 * 2 * HID * HID / 2;
  unsigned short* pWTb2 = (unsigned short*)(ws + off); off += (size_t)2 * HID * HID / 2;
  unsigned short* qkt_hi = (unsigned short*)(ws + off); off += (size_t)2 * 16 * HID / 2;
  unsigned short* qkt_lo = (unsigned short*)(ws + off); off += (size_t)2 * 16 * HID / 2;
  float* Qf  = ws + off; off += 2 * HID * HEADS;
  float* Kf  = ws + off; off += 2 * HID * HEADS;
  float* cbf = ws + off; off += 2 * HID;
  float* pbf = ws + off; off += 2 * HID;
  float* bo2 = ws + off; off += 2 * HID;

  // ---- detect + convert ----
  detect_kernel<<<1, 256, 0, stream>>>((const unsigned short*)x, eidx, flags);
  zero_int_kernel<<<(2 * NPAD + 255) / 256, 256, 0, stream>>>(deg, 2 * NPAD);   // deg + cnt
  cvt_idx_hist_kernel<<<(E_EDGES + 255) / 256, 256, 0, stream>>>(eidx, etype, dstA, pk, deg, flags);
  cvt_xb_kernel<<<(N_NODES * HID + 255) / 256, 256, 0, stream>>>(x, hb, N_NODES * HID, flags);
  cvt_wt_kernel<<<(2 * 2 * HID * HID + 255) / 256, 256, 0, stream>>>(d_in[iW[0]], d_in[iW[1]], Wbt, flags);
  {
    P8 tab;
    float* base = ws;
    for (int l = 0; l < 2; ++l) {
      tab.src[l * 4 + 0] = d_in[iQ[l]];  tab.dstoff[l * 4 + 0] = (int)(Qf - base) + l * HID * HEADS;  tab.n[l * 4 + 0] = HID * HEADS;
      tab.src[l * 4 + 1] = d_in[iK[l]];  tab.dstoff[l * 4 + 1] = (int)(Kf - base) + l * HID * HEADS;  tab.n[l * 4 + 1] = HID * HEADS;
      tab.src[l * 4 + 2] = d_in[icb[l]]; tab.dstoff[l * 4 + 2] = (int)(cbf - base) + l * HID;         tab.n[l * 4 + 2] = HID;
      tab.src[l * 4 + 3] = d_in[ipb[l]]; tab.dstoff[l * 4 + 3] = (int)(pbf - base) + l * HID;         tab.n[l * 4 + 3] = HID;
    }
    cvt_params_kernel<<<2, 256, 0, stream>>>(tab, base, flags);
  }

  // ---- counting sort by dst ----
  scan1_kernel<<<SCAN_B, 256, 0, stream>>>(deg, excl, bsum);
  scan23_kernel<<<SCAN_B, 256, 0, stream>>>(excl, bsum, rowstart);
  scatter_kernel<<<(E_EDGES + 255) / 256, 256, 0, stream>>>(dstA, pk, rowstart, cnt, eord);

  // ---- folded params ----
  prep_wq_kernel<<<2, 256, 0, stream>>>(Wbt, Qf, Kf, qkt_hi, qkt_lo);
  prep_proj_kernel<<<2 * HID, 64, 0, stream>>>(d_in[ipW[0]], d_in[ipW[1]], cbf, pbf, pWTb2, bo2, flags);

  const int RB = NPAD / 64;   // 782 row-blocks
  const int QB = (NPAD + 255) / 256;
  for (int l = 0; l < 2; ++l) {
    gemm_xw_mfma<<<RB, 256, 0, stream>>>(hb, Wbt + (size_t)l * 2 * HID * HID, xw);
    qk_mfma_kernel<<<QB, 256, 0, stream>>>(hb, qkt_hi + (size_t)l * 16 * HID, qkt_lo + (size_t)l * 16 * HID,
                                           (float4*)qi, (float4*)kj);
    edge_fused_kernel<<<N_NODES / 4, 256, 0, stream>>>(rowstart, eord, (const float4*)qi, (const float4*)kj, xw, aggb);
    proj_mfma<<<RB, 128, 0, stream>>>(aggb, pWTb2 + (size_t)l * HID * HID, bo2 + l * HID, hb,
                                      (l == 1) ? d_out : nullptr, flags);
  }
}

// Round 9
// 373.122 us; speedup vs baseline: 1.0516x; 1.0516x over previous
//
#include <hip/hip_runtime.h>
#include <hip/hip_bf16.h>

typedef __hip_bfloat16 bf16;
typedef short s16x8 __attribute__((ext_vector_type(8)));
typedef float f32x4 __attribute__((ext_vector_type(4)));

#define N_NODES 50000
#define NPAD    50048          // multiple of 64
#define E_EDGES 600000
#define HID     128
#define HEADS   4
#define SCAN_B  196            // ceil(NPAD/256)

// ---- float -> bf16 bits (RNE), finite inputs only ----
__device__ __forceinline__ unsigned short f2bf_bits(float f) {
  unsigned u = __float_as_uint(f);
  u += 0x7fffu + ((u >> 16) & 1u);
  return (unsigned short)(u >> 16);
}
__device__ __forceinline__ float bf2f(unsigned short b) {
  return __uint_as_float(((unsigned)b) << 16);
}
// packed-dword bf16 pair -> floats (1 op each)
__device__ __forceinline__ float lo_f(unsigned v) { return __uint_as_float(v << 16); }
__device__ __forceinline__ float hi_f(unsigned v) { return __uint_as_float(v & 0xffff0000u); }

__device__ __forceinline__ float lrelu(float v) { return v >= 0.f ? v : 0.2f * v; }

// ---- runtime dtype detection ----
__global__ __launch_bounds__(256) void detect_kernel(const unsigned short* __restrict__ xb,
                                                     const int* __restrict__ ei,
                                                     int* __restrict__ flags) {
  int t = threadIdx.x;
  __shared__ int cnt[2];
  if (t < 2) cnt[t] = 0;
  __syncthreads();
  unsigned short v = xb[2 * t];
  int ex = (v >> 7) & 0xFF;
  if (ex < 119 || ex > 135) atomicAdd(&cnt[0], 1);
  if (ei[2 * t + 1] != 0) atomicAdd(&cnt[1], 1);
  __syncthreads();
  if (t == 0) {
    flags[0] = (cnt[0] > 64) ? 1 : 0;
    flags[1] = (cnt[1] == 0) ? 1 : 0;
  }
}

__global__ __launch_bounds__(256) void zero_int_kernel(int* __restrict__ p, int n) {
  int i = blockIdx.x * 256 + threadIdx.x;
  if (i < n) p[i] = 0;
}

// ---- index conversion + degree histogram ----
__global__ __launch_bounds__(256) void cvt_idx_hist_kernel(const int* __restrict__ eidx,
                                                           const int* __restrict__ etype,
                                                           int* __restrict__ dstA, int* __restrict__ pk,
                                                           int* __restrict__ deg,
                                                           const int* __restrict__ flags) {
  int e = blockIdx.x * 256 + threadIdx.x;
  if (e >= E_EDGES) return;
  int s, d, r;
  if (flags[1]) {
    const long long* e64 = (const long long*)eidx;
    const long long* t64 = (const long long*)etype;
    s = (int)e64[e]; d = (int)e64[E_EDGES + e]; r = (int)t64[e];
  } else {
    s = eidx[e]; d = eidx[E_EDGES + e]; r = etype[e];
  }
  dstA[e] = d;
  pk[e] = s | (r << 16);
  atomicAdd(&deg[d], 1);
}

// ---- float-tensor -> bf16 bits ----
__global__ __launch_bounds__(256) void cvt_xb_kernel(const void* __restrict__ src,
                                                     unsigned short* __restrict__ dst, int n,
                                                     const int* __restrict__ flags) {
  int i = blockIdx.x * 256 + threadIdx.x;
  if (i >= n) return;
  if (flags[0]) dst[i] = f2bf_bits(((const float*)src)[i]);
  else          dst[i] = ((const unsigned short*)src)[i];
}

// ---- W (both layers) -> bf16 N-major [l][r][o][i] ----
__global__ __launch_bounds__(256) void cvt_wt_kernel(const void* __restrict__ src0,
                                                     const void* __restrict__ src1,
                                                     unsigned short* __restrict__ dst,
                                                     const int* __restrict__ flags) {
  int idx = blockIdx.x * 256 + threadIdx.x;
  if (idx >= 2 * 2 * HID * HID) return;
  int l = idx >> 15, rem = idx & 32767;
  int r = rem >> 14, i = (rem >> 7) & 127, o = rem & 127;
  const void* src = l ? src1 : src0;
  unsigned short b;
  if (flags[0]) b = f2bf_bits(((const float*)src)[rem]);
  else          b = ((const unsigned short*)src)[rem];
  dst[(size_t)l * 2 * HID * HID + ((size_t)r * HID + o) * HID + i] = b;
}

// ---- small params -> fp32 block ----
struct P8 { const void* src[8]; int dstoff[8]; int n[8]; };
__global__ __launch_bounds__(256) void cvt_params_kernel(P8 tab, float* __restrict__ base,
                                                         const int* __restrict__ flags) {
  const int f = flags[0];
  for (int k = 0; k < 8; ++k) {
    int n = tab.n[k];
    for (int i = blockIdx.x * 256 + threadIdx.x; i < n; i += gridDim.x * 256) {
      float v = f ? ((const float*)tab.src[k])[i] : bf2f(((const unsigned short*)tab.src[k])[i]);
      base[tab.dstoff[k] + i] = v;
    }
  }
}

// ---- scan stage 1 ----
__global__ __launch_bounds__(256) void scan1_kernel(const int* __restrict__ deg,
                                                    int* __restrict__ excl,
                                                    int* __restrict__ bsum) {
  __shared__ int sm[256];
  int t = threadIdx.x, i = blockIdx.x * 256 + t;
  int v = (i < NPAD) ? deg[i] : 0;
  sm[t] = v;
  __syncthreads();
#pragma unroll
  for (int off = 1; off < 256; off <<= 1) {
    int add = (t >= off) ? sm[t - off] : 0;
    __syncthreads();
    sm[t] += add;
    __syncthreads();
  }
  if (i < NPAD) excl[i] = sm[t] - v;
  if (t == 255) bsum[blockIdx.x] = sm[255];
}

// ---- scan stages 2+3 fused ----
__global__ __launch_bounds__(256) void scan23_kernel(const int* __restrict__ excl,
                                                     const int* __restrict__ bsum,
                                                     int* __restrict__ rowstart) {
  __shared__ int sm[256];
  int t = threadIdx.x;
  int v = (t < SCAN_B) ? bsum[t] : 0;
  sm[t] = v;
  __syncthreads();
#pragma unroll
  for (int off = 1; off < 256; off <<= 1) {
    int add = (t >= off) ? sm[t - off] : 0;
    __syncthreads();
    sm[t] += add;
    __syncthreads();
  }
  int bpre = (blockIdx.x > 0) ? sm[blockIdx.x - 1] : 0;
  int i = blockIdx.x * 256 + t;
  if (i < NPAD) rowstart[i] = excl[i] + bpre;
  if (i == 0) rowstart[NPAD] = E_EDGES;
}

__global__ __launch_bounds__(256) void scatter_kernel(const int* __restrict__ dstA,
                                                      const int* __restrict__ pk,
                                                      const int* __restrict__ rowstart,
                                                      int* __restrict__ cnt,
                                                      int* __restrict__ eord) {
  int e = blockIdx.x * 256 + threadIdx.x;
  if (e >= E_EDGES) return;
  int d = dstA[e];
  int pos = rowstart[d] + atomicAdd(&cnt[d], 1);
  eord[pos] = pk[e];
}

// ====== GEMM: LDS-staged A (once per block), register-prefetched B ======
// A rows are contiguous in memory -> 16 KB coalesced stage; +16B row pad
// keeps ds_read_b128 ~2-way (free). Removes the 4x redundant fragmented
// A-loads that made R7's full-prefetch regress on the 4-wave kernel.

// ---- xw[r,n,:] = h[n,:] @ W[r]; 4 waves = 4 (r,colpanel) of SAME 64 rows ----
__global__ __launch_bounds__(256) void gemm_xw_mfma(const unsigned short* __restrict__ hb,
                                                    const unsigned short* __restrict__ Wbt,
                                                    unsigned short* __restrict__ xw) {
  __shared__ unsigned short As[64][136];
  const int t = threadIdx.x;
  const int wave = t >> 6, lane = t & 63;
  const int row0 = blockIdx.x * 64;
  const int r = wave >> 1, colb = (wave & 1) * 64;
  const int lm = lane & 15, q = lane >> 4;
  // B prefetch (weights; L1/L2-resident after first blocks)
  const unsigned short* Bt = Wbt + (size_t)r * HID * HID;
  s16x8 bfr[4][4];
#pragma unroll
  for (int kc = 0; kc < 4; ++kc) {
    const int ko = kc * 32 + q * 8;
#pragma unroll
    for (int ct = 0; ct < 4; ++ct)
      bfr[kc][ct] = *(const s16x8*)(Bt + (size_t)(colb + ct * 16 + lm) * HID + ko);
  }
  // stage A tile (contiguous 16 KB) -> LDS
  const unsigned short* gsrc = hb + (size_t)row0 * HID;
#pragma unroll
  for (int j = 0; j < 4; ++j) {
    int idx = j * 256 + t;                      // 16B units, 1024 total
    *(s16x8*)&As[idx >> 4][(idx & 15) * 8] = *(const s16x8*)(gsrc + idx * 8);
  }
  __syncthreads();
  f32x4 acc[4][4];
#pragma unroll
  for (int a = 0; a < 4; ++a)
#pragma unroll
    for (int b = 0; b < 4; ++b) { f32x4 z = {0.f, 0.f, 0.f, 0.f}; acc[a][b] = z; }
#pragma unroll
  for (int kc = 0; kc < 4; ++kc) {
    const int ko = kc * 32 + q * 8;
#pragma unroll
    for (int rt = 0; rt < 4; ++rt) {
      s16x8 a = *(const s16x8*)&As[rt * 16 + lm][ko];
#pragma unroll
      for (int ct = 0; ct < 4; ++ct)
        acc[rt][ct] = __builtin_amdgcn_mfma_f32_16x16x32_bf16(a, bfr[kc][ct], acc[rt][ct], 0, 0, 0);
    }
  }
#pragma unroll
  for (int rt = 0; rt < 4; ++rt)
#pragma unroll
    for (int i = 0; i < 4; ++i) {
      int row = row0 + rt * 16 + q * 4 + i;
      if (row < N_NODES) {
#pragma unroll
        for (int ct = 0; ct < 4; ++ct) {
          int o = colb + ct * 16 + lm;
          xw[((size_t)r * NPAD + row) * HID + o] = f2bf_bits(acc[rt][ct][i]);
        }
      }
    }
}

// ---- out[n,o] = elu( agg[n,:] @ pW.T + bo ); 2 waves = 2 col panels ----
__global__ __launch_bounds__(128) void proj_mfma(const unsigned short* __restrict__ aggb,
                                                 const unsigned short* __restrict__ pWTb,
                                                 const float* __restrict__ bo,
                                                 unsigned short* __restrict__ hbout,
                                                 void* __restrict__ dout,
                                                 const int* __restrict__ flags) {
  __shared__ unsigned short As[64][136];
  const int t = threadIdx.x;
  const int wave = t >> 6, lane = t & 63;
  const int row0 = blockIdx.x * 64;
  const int colb = wave * 64;
  const int lm = lane & 15, q = lane >> 4;
  s16x8 bfr[4][4];
#pragma unroll
  for (int kc = 0; kc < 4; ++kc) {
    const int ko = kc * 32 + q * 8;
#pragma unroll
    for (int ct = 0; ct < 4; ++ct)
      bfr[kc][ct] = *(const s16x8*)(pWTb + (size_t)(colb + ct * 16 + lm) * HID + ko);
  }
  const unsigned short* gsrc = aggb + (size_t)row0 * HID;
#pragma unroll
  for (int j = 0; j < 8; ++j) {
    int idx = j * 128 + t;
    *(s16x8*)&As[idx >> 4][(idx & 15) * 8] = *(const s16x8*)(gsrc + idx * 8);
  }
  __syncthreads();
  f32x4 acc[4][4];
#pragma unroll
  for (int a = 0; a < 4; ++a)
#pragma unroll
    for (int b = 0; b < 4; ++b) { f32x4 z = {0.f, 0.f, 0.f, 0.f}; acc[a][b] = z; }
#pragma unroll
  for (int kc = 0; kc < 4; ++kc) {
    const int ko = kc * 32 + q * 8;
#pragma unroll
    for (int rt = 0; rt < 4; ++rt) {
      s16x8 a = *(const s16x8*)&As[rt * 16 + lm][ko];
#pragma unroll
      for (int ct = 0; ct < 4; ++ct)
        acc[rt][ct] = __builtin_amdgcn_mfma_f32_16x16x32_bf16(a, bfr[kc][ct], acc[rt][ct], 0, 0, 0);
    }
  }
  const int f32out = flags[0];
#pragma unroll
  for (int rt = 0; rt < 4; ++rt)
#pragma unroll
    for (int i = 0; i < 4; ++i) {
      int row = row0 + rt * 16 + q * 4 + i;
      if (row < N_NODES) {
#pragma unroll
        for (int ct = 0; ct < 4; ++ct) {
          int o = colb + ct * 16 + lm;
          float v = acc[rt][ct][i] + bo[o];
          v = v > 0.f ? v : expm1f(v);       // ELU
          size_t idx = (size_t)row * HID + o;
          if (dout) {
            if (f32out) ((float*)dout)[idx] = v;
            else        ((unsigned short*)dout)[idx] = f2bf_bits(v);
          } else {
            hbout[idx] = f2bf_bits(v);
          }
        }
      }
    }
}

// ---- WQ/WK fold -> split-bf16 table qkt[l][out16][128] ----
__global__ __launch_bounds__(256) void prep_wq_kernel(const unsigned short* __restrict__ Wbt,
                                                      const float* __restrict__ Qf,
                                                      const float* __restrict__ Kf,
                                                      unsigned short* __restrict__ qkt_hi,
                                                      unsigned short* __restrict__ qkt_lo) {
  int idx = blockIdx.x * 256 + threadIdx.x;   // (l,r,i)
  if (idx >= 2 * 2 * HID) return;
  int i = idx & 127, lr = idx >> 7, l = lr >> 1, r = (lr & 1);
  float aq[4] = {0.f, 0.f, 0.f, 0.f}, ak[4] = {0.f, 0.f, 0.f, 0.f};
  const unsigned short* Wb = Wbt + (size_t)lr * HID * HID;   // [o=j][i]
  const float* Qp = Qf + l * HID * HEADS;
  const float* Kp = Kf + l * HID * HEADS;
  for (int j = 0; j < HID; ++j) {
    float w = bf2f(Wb[j * HID + i]);
    float4 q4 = *(const float4*)(Qp + j * 4);
    float4 k4 = *(const float4*)(Kp + j * 4);
    aq[0] += w * q4.x; aq[1] += w * q4.y; aq[2] += w * q4.z; aq[3] += w * q4.w;
    ak[0] += w * k4.x; ak[1] += w * k4.y; ak[2] += w * k4.z; ak[3] += w * k4.w;
  }
  size_t base = (size_t)l * 16 * HID;
#pragma unroll
  for (int h = 0; h < 4; ++h) {
    unsigned short qh = f2bf_bits(aq[h]);
    unsigned short kh = f2bf_bits(ak[h]);
    float qres = aq[h] - bf2f(qh);
    float kres = ak[h] - bf2f(kh);
    qkt_hi[base + (size_t)(r * 4 + h) * HID + i] = qh;
    qkt_lo[base + (size_t)(r * 4 + h) * HID + i] = f2bf_bits(qres);
    qkt_hi[base + (size_t)(8 + r * 4 + h) * HID + i] = kh;
    qkt_lo[base + (size_t)(8 + r * 4 + h) * HID + i] = f2bf_bits(kres);
  }
}

// ---- qk via MFMA: [64 nodes]x[16 outs] per wave, split-bf16 B ----
__global__ __launch_bounds__(256) void qk_mfma_kernel(const unsigned short* __restrict__ hb,
                                                      const unsigned short* __restrict__ qkt_hi,
                                                      const unsigned short* __restrict__ qkt_lo,
                                                      float4* __restrict__ qi4,
                                                      float4* __restrict__ kj4) {
  __shared__ float st[4][16][68];
  const int wave = threadIdx.x >> 6, lane = threadIdx.x & 63;
  const int row0 = blockIdx.x * 256 + wave * 64;
  const int lm = lane & 15, q = lane >> 4;
  if (row0 < NPAD) {
    s16x8 bhi[4], blo[4], af[4][4];
#pragma unroll
    for (int kc = 0; kc < 4; ++kc) {
      const int ko = kc * 32 + q * 8;
      bhi[kc] = *(const s16x8*)(qkt_hi + (size_t)lm * HID + ko);
      blo[kc] = *(const s16x8*)(qkt_lo + (size_t)lm * HID + ko);
    }
#pragma unroll
    for (int kc = 0; kc < 4; ++kc) {
      const int ko = kc * 32 + q * 8;
#pragma unroll
      for (int rt = 0; rt < 4; ++rt)
        af[kc][rt] = *(const s16x8*)(hb + (size_t)(row0 + rt * 16 + lm) * HID + ko);
    }
    f32x4 acc[4];
#pragma unroll
    for (int a = 0; a < 4; ++a) { f32x4 z = {0.f, 0.f, 0.f, 0.f}; acc[a] = z; }
#pragma unroll
    for (int kc = 0; kc < 4; ++kc)
#pragma unroll
      for (int rt = 0; rt < 4; ++rt) {
        acc[rt] = __builtin_amdgcn_mfma_f32_16x16x32_bf16(af[kc][rt], bhi[kc], acc[rt], 0, 0, 0);
        acc[rt] = __builtin_amdgcn_mfma_f32_16x16x32_bf16(af[kc][rt], blo[kc], acc[rt], 0, 0, 0);
      }
#pragma unroll
    for (int rt = 0; rt < 4; ++rt)
      *(f32x4*)&st[wave][lm][rt * 16 + q * 4] = acc[rt];
  }
  __syncthreads();
  if (row0 < NPAD) {
    int n = row0 + lane;
    if (n < N_NODES) {
      float4 v;
      v.x = st[wave][0][lane]; v.y = st[wave][1][lane]; v.z = st[wave][2][lane]; v.w = st[wave][3][lane];
      qi4[n] = v;
      v.x = st[wave][4][lane]; v.y = st[wave][5][lane]; v.z = st[wave][6][lane]; v.w = st[wave][7][lane];
      qi4[NPAD + n] = v;
      v.x = st[wave][8][lane]; v.y = st[wave][9][lane]; v.z = st[wave][10][lane]; v.w = st[wave][11][lane];
      kj4[n] = v;
      v.x = st[wave][12][lane]; v.y = st[wave][13][lane]; v.z = st[wave][14][lane]; v.w = st[wave][15][lane];
      kj4[NPAD + n] = v;
    }
  }
}

// ---- fused per-dst-node: alpha -> segment softmax -> weighted aggregate ----
// wls transposed to [wave][j][72]: stores lane-contiguous (2-way, free),
// reads broadcast with hh-groups on distinct banks (R7 had 1.2M conflicts).
__global__ __launch_bounds__(256) void edge_fused_kernel(
    const int* __restrict__ rowstart, const int* __restrict__ eord,
    const float4* __restrict__ qi4, const float4* __restrict__ kj4,
    const unsigned short* __restrict__ xw, unsigned short* __restrict__ aggb) {
  __shared__ volatile float wls[4][4][72];
  const int wave = threadIdx.x >> 6, lane = threadIdx.x & 63;
  const int n = blockIdx.x * 4 + wave;          // N_NODES % 4 == 0
  unsigned* outp = (unsigned*)(aggb + ((size_t)n << 7)) + lane;
  const int start = rowstart[n];
  const int deg = rowstart[n + 1] - start;
  if (deg == 0) { *outp = 0u; return; }
  const int hh = lane >> 4;
  const int ch2 = lane << 1;                    // ushort offset within a row
  float2 acc = {0.f, 0.f};
  float ssel;
  if (deg <= 64) {
    int p = 0;
    float a0 = -1e30f, a1 = -1e30f, a2 = -1e30f, a3 = -1e30f;
    if (lane < deg) {
      p = eord[start + lane];
      int s = p & 0xffff, r = p >> 16;
      float4 k4 = kj4[r ? (NPAD + s) : s];
      float4 q4 = r ? qi4[NPAD + n] : qi4[n];
      a0 = lrelu(q4.x + k4.x); a1 = lrelu(q4.y + k4.y);
      a2 = lrelu(q4.z + k4.z); a3 = lrelu(q4.w + k4.w);
    }
    float m0 = a0, m1 = a1, m2 = a2, m3 = a3;
#pragma unroll
    for (int off = 32; off > 0; off >>= 1) {
      m0 = fmaxf(m0, __shfl_xor(m0, off)); m1 = fmaxf(m1, __shfl_xor(m1, off));
      m2 = fmaxf(m2, __shfl_xor(m2, off)); m3 = fmaxf(m3, __shfl_xor(m3, off));
    }
    float w0 = 0.f, w1 = 0.f, w2 = 0.f, w3 = 0.f;
    if (lane < deg) {
      w0 = __expf(a0 - m0); w1 = __expf(a1 - m1);
      w2 = __expf(a2 - m2); w3 = __expf(a3 - m3);
    }
    float s0 = w0, s1 = w1, s2 = w2, s3 = w3;
#pragma unroll
    for (int off = 32; off > 0; off >>= 1) {
      s0 += __shfl_xor(s0, off); s1 += __shfl_xor(s1, off);
      s2 += __shfl_xor(s2, off); s3 += __shfl_xor(s3, off);
    }
    ssel = hh == 0 ? s0 : hh == 1 ? s1 : hh == 2 ? s2 : s3;
    wls[wave][0][lane] = w0;
    wls[wave][1][lane] = w1;
    wls[wave][2][lane] = w2;
    wls[wave][3][lane] = w3;
    volatile const float* wrh = &wls[wave][hh][0];   // broadcast reads
    const int degp = (deg + 7) & ~7;            // pad lanes: w=0, p=0 (row 0)
#pragma unroll 1
    for (int e = 0; e < degp; e += 8) {
      int pp[8];
      unsigned vv[8];
#pragma unroll
      for (int u = 0; u < 8; ++u)
        pp[u] = __builtin_amdgcn_readlane(p, e + u);
#pragma unroll
      for (int u = 0; u < 8; ++u)
        vv[u] = *(const unsigned*)(xw + ((size_t)((pp[u] & 0xffff) + (pp[u] >> 16) * NPAD) << 7) + ch2);
#pragma unroll
      for (int u = 0; u < 8; ++u) {
        float we = wrh[e + u];
        acc.x = fmaf(lo_f(vv[u]), we, acc.x);
        acc.y = fmaf(hi_f(vv[u]), we, acc.y);
      }
    }
  } else {
    // ---- generic fallback (deg > 64): wave-uniform serial, rare ----
    const float4 q0 = qi4[n], q1 = qi4[NPAD + n];
    float4 m = make_float4(-1e30f, -1e30f, -1e30f, -1e30f);
    for (int e = start; e < start + deg; ++e) {
      int pe = eord[e];
      int s = pe & 0xffff, r = pe >> 16;
      float4 k4 = kj4[(size_t)r * NPAD + s];
      float4 q4 = r ? q1 : q0;
      m.x = fmaxf(m.x, lrelu(q4.x + k4.x)); m.y = fmaxf(m.y, lrelu(q4.y + k4.y));
      m.z = fmaxf(m.z, lrelu(q4.z + k4.z)); m.w = fmaxf(m.w, lrelu(q4.w + k4.w));
    }
    float4 sv = make_float4(0.f, 0.f, 0.f, 0.f);
    for (int e = start; e < start + deg; ++e) {
      int pe = eord[e];
      int s = pe & 0xffff, r = pe >> 16;
      float4 k4 = kj4[(size_t)r * NPAD + s];
      float4 q4 = r ? q1 : q0;
      float w0 = __expf(lrelu(q4.x + k4.x) - m.x);
      float w1 = __expf(lrelu(q4.y + k4.y) - m.y);
      float w2 = __expf(lrelu(q4.z + k4.z) - m.z);
      float w3 = __expf(lrelu(q4.w + k4.w) - m.w);
      sv.x += w0; sv.y += w1; sv.z += w2; sv.w += w3;
      float we = hh == 0 ? w0 : hh == 1 ? w1 : hh == 2 ? w2 : w3;
      unsigned v = *(const unsigned*)(xw + (((size_t)r * NPAD + s) << 7) + ch2);
      acc.x = fmaf(lo_f(v), we, acc.x);
      acc.y = fmaf(hi_f(v), we, acc.y);
    }
    ssel = hh == 0 ? sv.x : hh == 1 ? sv.y : hh == 2 ? sv.z : sv.w;
  }
  float inv = 1.f / (ssel + 1e-16f);
  *outp = (unsigned)f2bf_bits(acc.x * inv) | ((unsigned)f2bf_bits(acc.y * inv) << 16);
}

// ---- both layers: pWTb2 + folded bias ----
__global__ __launch_bounds__(64) void prep_proj_kernel(const void* __restrict__ pW0,
                                                       const void* __restrict__ pW1,
                                                       const float* __restrict__ cbf,
                                                       const float* __restrict__ pbf,
                                                       unsigned short* __restrict__ pWTb2,
                                                       float* __restrict__ bo2,
                                                       const int* __restrict__ flags) {
  int o = blockIdx.x & 127, l = blockIdx.x >> 7, t = threadIdx.x;
  const void* pWraw = l ? pW1 : pW0;
  const float* cb = cbf + l * HID;
  const int f = flags[0];
  float part = 0.f;
#pragma unroll
  for (int i = t; i < HID; i += 64) {
    float w = f ? ((const float*)pWraw)[o * HID + i] : bf2f(((const unsigned short*)pWraw)[o * HID + i]);
    pWTb2[(size_t)l * HID * HID + o * HID + i] = f2bf_bits(w);
    part += cb[i] * w;
  }
#pragma unroll
  for (int off = 32; off > 0; off >>= 1) part += __shfl_xor(part, off);
  if (t == 0) bo2[l * HID + o] = pbf[l * HID + o] + part;
}

extern "C" void kernel_launch(void* const* d_in, const int* in_sizes, int n_in,
                              void* d_out, int out_size, void* d_ws, size_t ws_size,
                              hipStream_t stream) {
  const void* x     = d_in[0];
  const int*  eidx  = (const int*)d_in[1];
  const int*  etype = (const int*)d_in[2];
  const int iW[2] = {3, 9}, iQ[2] = {4, 10}, iK[2] = {5, 11}, icb[2] = {6, 12}, ipW[2] = {7, 13}, ipb[2] = {8, 14};

  float* ws = (float*)d_ws;
  size_t off = 0;
  int*   flags = (int*)(ws + off); off += 16;
  unsigned short* hb   = (unsigned short*)(ws + off); off += (size_t)NPAD * HID / 2;
  unsigned short* xw   = (unsigned short*)(ws + off); off += (size_t)NPAD * HID;       // [2][NPAD][128] bf16
  float* qi   = ws + off; off += (size_t)2 * NPAD * HEADS;
  float* kj   = ws + off; off += (size_t)2 * NPAD * HEADS;
  unsigned short* aggb = (unsigned short*)(ws + off); off += (size_t)NPAD * HID / 2;
  int* dstA = (int*)(ws + off); off += E_EDGES;
  int* pk   = (int*)(ws + off); off += E_EDGES;
  int* eord = (int*)(ws + off); off += E_EDGES;
  int* deg  = (int*)(ws + off); off += NPAD;        // deg|cnt contiguous for one zero pass
  int* cnt  = (int*)(ws + off); off += NPAD;
  int* excl = (int*)(ws + off); off += NPAD;
  int* rowstart = (int*)(ws + off); off += NPAD + 16;
  int* bsum  = (int*)(ws + off); off += 256;
  unsigned short* Wbt   = (unsigned short*)(ws + off); off += (size_t)2 * 2 * HID * HID / 2;
  unsigned short* pWTb2 = (unsigned short*)(ws + off); off += (size_t)2 * HID * HID / 2;
  unsigned short* qkt_hi = (unsigned short*)(ws + off); off += (size_t)2 * 16 * HID / 2;
  unsigned short* qkt_lo = (unsigned short*)(ws + off); off += (size_t)2 * 16 * HID / 2;
  float* Qf  = ws + off; off += 2 * HID * HEADS;
  float* Kf  = ws + off; off += 2 * HID * HEADS;
  float* cbf = ws + off; off += 2 * HID;
  float* pbf = ws + off; off += 2 * HID;
  float* bo2 = ws + off; off += 2 * HID;

  // ---- detect + convert ----
  detect_kernel<<<1, 256, 0, stream>>>((const unsigned short*)x, eidx, flags);
  zero_int_kernel<<<(2 * NPAD + 255) / 256, 256, 0, stream>>>(deg, 2 * NPAD);   // deg + cnt
  cvt_idx_hist_kernel<<<(E_EDGES + 255) / 256, 256, 0, stream>>>(eidx, etype, dstA, pk, deg, flags);
  cvt_xb_kernel<<<(N_NODES * HID + 255) / 256, 256, 0, stream>>>(x, hb, N_NODES * HID, flags);
  cvt_wt_kernel<<<(2 * 2 * HID * HID + 255) / 256, 256, 0, stream>>>(d_in[iW[0]], d_in[iW[1]], Wbt, flags);
  {
    P8 tab;
    float* base = ws;
    for (int l = 0; l < 2; ++l) {
      tab.src[l * 4 + 0] = d_in[iQ[l]];  tab.dstoff[l * 4 + 0] = (int)(Qf - base) + l * HID * HEADS;  tab.n[l * 4 + 0] = HID * HEADS;
      tab.src[l * 4 + 1] = d_in[iK[l]];  tab.dstoff[l * 4 + 1] = (int)(Kf - base) + l * HID * HEADS;  tab.n[l * 4 + 1] = HID * HEADS;
      tab.src[l * 4 + 2] = d_in[icb[l]]; tab.dstoff[l * 4 + 2] = (int)(cbf - base) + l * HID;         tab.n[l * 4 + 2] = HID;
      tab.src[l * 4 + 3] = d_in[ipb[l]]; tab.dstoff[l * 4 + 3] = (int)(pbf - base) + l * HID;         tab.n[l * 4 + 3] = HID;
    }
    cvt_params_kernel<<<2, 256, 0, stream>>>(tab, base, flags);
  }

  // ---- counting sort by dst ----
  scan1_kernel<<<SCAN_B, 256, 0, stream>>>(deg, excl, bsum);
  scan23_kernel<<<SCAN_B, 256, 0, stream>>>(excl, bsum, rowstart);
  scatter_kernel<<<(E_EDGES + 255) / 256, 256, 0, stream>>>(dstA, pk, rowstart, cnt, eord);

  // ---- folded params ----
  prep_wq_kernel<<<2, 256, 0, stream>>>(Wbt, Qf, Kf, qkt_hi, qkt_lo);
  prep_proj_kernel<<<2 * HID, 64, 0, stream>>>(d_in[ipW[0]], d_in[ipW[1]], cbf, pbf, pWTb2, bo2, flags);

  const int RB = NPAD / 64;   // 782 row-blocks
  const int QB = (NPAD + 255) / 256;
  for (int l = 0; l < 2; ++l) {
    gemm_xw_mfma<<<RB, 256, 0, stream>>>(hb, Wbt + (size_t)l * 2 * HID * HID, xw);
    qk_mfma_kernel<<<QB, 256, 0, stream>>>(hb, qkt_hi + (size_t)l * 16 * HID, qkt_lo + (size_t)l * 16 * HID,
                                           (float4*)qi, (float4*)kj);
    edge_fused_kernel<<<N_NODES / 4, 256, 0, stream>>>(rowstart, eord, (const float4*)qi, (const float4*)kj, xw, aggb);
    proj_mfma<<<RB, 128, 0, stream>>>(aggb, pWTb2 + (size_t)l * HID * HID, bo2 + l * HID, hb,
                                      (l == 1) ? d_out : nullptr, flags);
  }
}